// Round 1
// baseline (428.095 us; speedup 1.0000x reference)
//
#include <hip/hip_runtime.h>
#include <math.h>

// ---------------------------------------------------------------------------
// Stage 0: transpose conv weights (32,3,7,7) -> wT[147][32] for uniform loads
// ---------------------------------------------------------------------------
__global__ __launch_bounds__(256) void prep_wT(const float* __restrict__ conv_w,
                                               float* __restrict__ wT) {
    for (int idx = threadIdx.x; idx < 32 * 147; idx += 256) {
        int o = idx / 147;
        int k = idx - o * 147;
        wT[k * 32 + o] = conv_w[idx];
    }
}

// ---------------------------------------------------------------------------
// Stage 1: fused conv(7x7,s2,p3) + bias + relu + 16x16 avgpool
// grid (pxg=2, py=7, b=B), block 256. Each block: 4 pooling windows
// (px = pxg*4 .. +3), all 32 channels. Input patch 3 x 37 x 133 in LDS.
// ---------------------------------------------------------------------------
#define IMG_STRIDE 135
__global__ __launch_bounds__(256) void conv_pool(const float* __restrict__ img,
                                                 const float* __restrict__ wT,
                                                 const float* __restrict__ cb,
                                                 float* __restrict__ pooled) {
    __shared__ float simg[3 * 37 * IMG_STRIDE];
    __shared__ float spart[4][128];
    __shared__ float sbias[32];
    const int t = threadIdx.x;
    const int pxg = blockIdx.x, py = blockIdx.y, b = blockIdx.z;
    const int Y0 = 32 * py - 3, X0 = 128 * pxg - 3;
    if (t < 32) sbias[t] = cb[t];
    const float* ib = img + (size_t)b * 3 * 224 * 224;
    for (int idx = t; idx < 3 * 37 * 133; idx += 256) {
        int c = idx / (37 * 133);
        int rem = idx - c * (37 * 133);
        int r = rem / 133;
        int col = rem - r * 133;
        int gy = Y0 + r, gx = X0 + col;
        float v = 0.f;
        if ((unsigned)gy < 224u && (unsigned)gx < 224u)
            v = ib[(c * 224 + gy) * 224 + gx];
        simg[(c * 37 + r) * IMG_STRIDE + col] = v;
    }
    __syncthreads();
    const int iy = t >> 4, bix = t & 15;
    const int lane = t & 63, wid = t >> 6;

    for (int chunk = 0; chunk < 4; ++chunk) {
        const int ch0 = chunk * 8;
        float a[4][8];
#pragma unroll
        for (int p = 0; p < 4; ++p)
#pragma unroll
            for (int r = 0; r < 8; ++r) a[p][r] = sbias[ch0 + r];

        for (int c = 0; c < 3; ++c) {
            for (int ky = 0; ky < 7; ++ky) {
                const float* irow = &simg[(c * 37 + 2 * iy + ky) * IMG_STRIDE + 2 * bix];
                const float* wk = wT + ((c * 7 + ky) * 7) * 32 + ch0;
#pragma unroll
                for (int kx = 0; kx < 7; ++kx) {
                    float4 w0 = *(const float4*)(wk + kx * 32);
                    float4 w1 = *(const float4*)(wk + kx * 32 + 4);
                    float wv[8] = {w0.x, w0.y, w0.z, w0.w, w1.x, w1.y, w1.z, w1.w};
                    float iv[4];
                    iv[0] = irow[kx];
                    iv[1] = irow[kx + 32];
                    iv[2] = irow[kx + 64];
                    iv[3] = irow[kx + 96];
#pragma unroll
                    for (int p = 0; p < 4; ++p)
#pragma unroll
                        for (int r = 0; r < 8; ++r)
                            a[p][r] = fmaf(iv[p], wv[r], a[p][r]);
                }
            }
        }
        // relu + wave butterfly reduce (sum over the wave's 64 positions)
        float sel = 0.f;
#pragma unroll
        for (int p = 0; p < 4; ++p) {
#pragma unroll
            for (int r = 0; r < 8; ++r) {
                float v = fmaxf(a[p][r], 0.f);
                v += __shfl_xor(v, 32);
                v += __shfl_xor(v, 16);
                v += __shfl_xor(v, 8);
                v += __shfl_xor(v, 4);
                v += __shfl_xor(v, 2);
                v += __shfl_xor(v, 1);
                if (lane == p * 8 + r) sel = v;
            }
        }
        if (lane < 32) spart[wid][chunk * 32 + lane] = sel;
    }
    __syncthreads();
    if (t < 128) {
        int p = t >> 5, ch = t & 31;
        int off = (ch >> 3) * 32 + p * 8 + (ch & 7);
        float s = spart[0][off] + spart[1][off] + spart[2][off] + spart[3][off];
        int px = pxg * 4 + p;
        if (px < 7)
            pooled[(size_t)b * 1568 + ch * 49 + py * 7 + px] = s * (1.f / 256.f);
    }
}

// ---------------------------------------------------------------------------
// Stage 2: fc1  (B,1568)->(B,512), relu. wave per (output, 8-batch group)
// ---------------------------------------------------------------------------
__global__ __launch_bounds__(256) void fc1_k(const float* __restrict__ in,
                                             const float* __restrict__ w,
                                             const float* __restrict__ bias,
                                             float* __restrict__ out) {
    int gw = (blockIdx.x * 256 + threadIdx.x) >> 6;
    int lane = threadIdx.x & 63;
    int o = gw >> 4;          // 512 outputs
    int b0 = (gw & 15) * 8;   // batch group
    float acc[8] = {0, 0, 0, 0, 0, 0, 0, 0};
    const float4* wr = (const float4*)(w + (size_t)o * 1568);
    for (int i = lane; i < 392; i += 64) {
        float4 wv = wr[i];
#pragma unroll
        for (int j = 0; j < 8; ++j) {
            float4 xv = *(const float4*)(in + (size_t)(b0 + j) * 1568 + i * 4);
            acc[j] = fmaf(xv.x, wv.x, acc[j]);
            acc[j] = fmaf(xv.y, wv.y, acc[j]);
            acc[j] = fmaf(xv.z, wv.z, acc[j]);
            acc[j] = fmaf(xv.w, wv.w, acc[j]);
        }
    }
#pragma unroll
    for (int j = 0; j < 8; ++j) {
        acc[j] += __shfl_xor(acc[j], 32);
        acc[j] += __shfl_xor(acc[j], 16);
        acc[j] += __shfl_xor(acc[j], 8);
        acc[j] += __shfl_xor(acc[j], 4);
        acc[j] += __shfl_xor(acc[j], 2);
        acc[j] += __shfl_xor(acc[j], 1);
    }
    float v = 0.f;
#pragma unroll
    for (int j = 0; j < 8; ++j)
        if (lane == j) v = acc[j];
    if (lane < 8) out[(size_t)(b0 + lane) * 512 + o] = fmaxf(v + bias[o], 0.f);
}

// ---------------------------------------------------------------------------
// Stage 3: vlm = img_fc2(h1) + text_fc(text_emb[len]) + biases  -> (B,768)
// ---------------------------------------------------------------------------
__global__ __launch_bounds__(256) void vlm_k(const float* __restrict__ h1,
                                             const float* __restrict__ w2,
                                             const float* __restrict__ b2,
                                             const int* __restrict__ tlen,
                                             const float* __restrict__ temb,
                                             const float* __restrict__ tw,
                                             const float* __restrict__ tb,
                                             float* __restrict__ vlm) {
    int gw = (blockIdx.x * 256 + threadIdx.x) >> 6;
    int lane = threadIdx.x & 63;
    int o = gw >> 4;          // 768 outputs
    int b0 = (gw & 15) * 8;
    int rows[8];
#pragma unroll
    for (int j = 0; j < 8; ++j) {
        int r = tlen[b0 + j];
        rows[j] = min(max(r, 0), 9999);
    }
    float acc[8] = {0, 0, 0, 0, 0, 0, 0, 0};
    const float4* wr = (const float4*)(w2 + (size_t)o * 512);
    for (int i = lane; i < 128; i += 64) {
        float4 wv = wr[i];
#pragma unroll
        for (int j = 0; j < 8; ++j) {
            float4 xv = *(const float4*)(h1 + (size_t)(b0 + j) * 512 + i * 4);
            acc[j] = fmaf(xv.x, wv.x, acc[j]);
            acc[j] = fmaf(xv.y, wv.y, acc[j]);
            acc[j] = fmaf(xv.z, wv.z, acc[j]);
            acc[j] = fmaf(xv.w, wv.w, acc[j]);
        }
    }
    {
        const float4* wt4 = (const float4*)(tw + (size_t)o * 256);
        int i = lane;  // 64 chunks exactly
        float4 wv = wt4[i];
#pragma unroll
        for (int j = 0; j < 8; ++j) {
            float4 xv = *(const float4*)(temb + (size_t)rows[j] * 256 + i * 4);
            acc[j] = fmaf(xv.x, wv.x, acc[j]);
            acc[j] = fmaf(xv.y, wv.y, acc[j]);
            acc[j] = fmaf(xv.z, wv.z, acc[j]);
            acc[j] = fmaf(xv.w, wv.w, acc[j]);
        }
    }
#pragma unroll
    for (int j = 0; j < 8; ++j) {
        acc[j] += __shfl_xor(acc[j], 32);
        acc[j] += __shfl_xor(acc[j], 16);
        acc[j] += __shfl_xor(acc[j], 8);
        acc[j] += __shfl_xor(acc[j], 4);
        acc[j] += __shfl_xor(acc[j], 2);
        acc[j] += __shfl_xor(acc[j], 1);
    }
    float v = 0.f;
#pragma unroll
    for (int j = 0; j < 8; ++j)
        if (lane == j) v = acc[j];
    if (lane < 8) vlm[(size_t)(b0 + lane) * 768 + o] = v + b2[o] + tb[o];
}

// ---------------------------------------------------------------------------
// Stage 4: whole graph branch + attention pooling + fused token + heads
// one block per batch, 768 threads (12 waves). Each node's 64 features map
// to one full wave -> LN via shuffle reduce.
// ---------------------------------------------------------------------------
__global__ __launch_bounds__(768) void graph_head(
    const float* __restrict__ nfeat, const int* __restrict__ eidx,
    const float* __restrict__ e1w, const float* __restrict__ e1b,
    const float* __restrict__ e2w, const float* __restrict__ e2b,
    const float* __restrict__ gcw, const float* __restrict__ gcb,
    const float* __restrict__ lns, const float* __restrict__ lnb,
    const float* __restrict__ pjw, const float* __restrict__ pjb,
    const float* __restrict__ a1w, const float* __restrict__ a1b,
    const float* __restrict__ a2w, const float* __restrict__ a2b,
    const float* __restrict__ w1, const float* __restrict__ b1,
    const float* __restrict__ w2, const float* __restrict__ b2,
    const float* __restrict__ w3, const float* __restrict__ b3,
    const float* __restrict__ vlm, float* __restrict__ out) {
    __shared__ float nf[10][20];
    __shared__ float hx[10][64];
    __shared__ float xs[10][64];
    __shared__ float nb[10][64];
    __shared__ int se[18], de[18];
    __shared__ float gts[10][32];
    __shared__ __align__(16) float fu[768];
    __shared__ float h1s[6][128];
    __shared__ float h2s[6][64];
    __shared__ float a3[6][16];
    __shared__ float sv[10], swt[10];
    const int t = threadIdx.x;
    const int b = blockIdx.x;

    if (t < 190) {
        int n = t / 19, i = t - n * 19;
        nf[n][i] = nfeat[(size_t)(b * 10 + n) * 19 + i];
    }
    if (t < 36) {
        if (t < 18) se[t] = eidx[b * 36 + t];
        else de[t - 18] = eidx[b * 36 + t];
    }
    __syncthreads();

    const int n = t >> 6, o = t & 63;
    // enc1 + relu
    if (t < 640) {
        float acc = e1b[o];
#pragma unroll
        for (int i = 0; i < 19; ++i) acc = fmaf(nf[n][i], e1w[o * 19 + i], acc);
        hx[n][o] = fmaxf(acc, 0.f);
    }
    __syncthreads();
    // enc2 (no relu)
    if (t < 640) {
        float acc = e2b[o];
        for (int k = 0; k < 64; ++k) acc = fmaf(hx[n][k], e2w[o * 64 + k], acc);
        xs[n][o] = acc;
    }
    __syncthreads();

    // 3 GC layers
    for (int l = 0; l < 3; ++l) {
        if (t < 640) {
            float s = 0.f;
            int cnt = 0;
            for (int e = 0; e < 18; ++e) {
                if (de[e] == n) {
                    s += xs[se[e]][o];
                    cnt++;
                }
            }
            nb[n][o] = s / (float)(cnt > 1 ? cnt : 1);
        }
        __syncthreads();
        float xn = 0.f;
        if (t < 640) {
            const float* wrow = gcw + (size_t)(l * 64 + o) * 128;
            float v = gcb[l * 64 + o];
            for (int k = 0; k < 64; ++k) v = fmaf(xs[n][k], wrow[k], v);
            for (int k = 0; k < 64; ++k) v = fmaf(nb[n][k], wrow[64 + k], v);
            v += xs[n][o];  // residual
            // layernorm across the 64 features (this wave)
            float mu = v;
            mu += __shfl_xor(mu, 32);
            mu += __shfl_xor(mu, 16);
            mu += __shfl_xor(mu, 8);
            mu += __shfl_xor(mu, 4);
            mu += __shfl_xor(mu, 2);
            mu += __shfl_xor(mu, 1);
            mu *= (1.f / 64.f);
            float d = v - mu;
            float vr = d * d;
            vr += __shfl_xor(vr, 32);
            vr += __shfl_xor(vr, 16);
            vr += __shfl_xor(vr, 8);
            vr += __shfl_xor(vr, 4);
            vr += __shfl_xor(vr, 2);
            vr += __shfl_xor(vr, 1);
            vr *= (1.f / 64.f);
            xn = fmaxf(d / sqrtf(vr + 1e-5f) * lns[l * 64 + o] + lnb[l * 64 + o], 0.f);
        }
        __syncthreads();
        if (t < 640) xs[n][o] = xn;
        __syncthreads();
    }

    // proj -> graph tokens (10,32)
    if (t < 320) {
        int nn = t >> 5, j = t & 31;
        float g = pjb[j];
        for (int k = 0; k < 64; ++k) g = fmaf(xs[nn][k], pjw[j * 64 + k], g);
        gts[nn][j] = g;
    }
    __syncthreads();
    // attention scores
    if (t < 10) {
        float s = a2b[0];
        for (int h = 0; h < 16; ++h) {
            float z = a1b[h];
            for (int k = 0; k < 32; ++k) z = fmaf(gts[t][k], a1w[h * 32 + k], z);
            s = fmaf(tanhf(z), a2w[h], s);
        }
        sv[t] = s;
    }
    __syncthreads();
    if (t == 0) {
        float m = sv[0];
        for (int i = 1; i < 10; ++i) m = fmaxf(m, sv[i]);
        float sum = 0.f;
        float e[10];
        for (int i = 0; i < 10; ++i) {
            e[i] = expf(sv[i] - m);
            sum += e[i];
        }
        for (int i = 0; i < 10; ++i) swt[i] = e[i] / sum;
    }
    __syncthreads();
    // fused token (768): vlm + robot_token on first 32 dims
    {
        float v = vlm[(size_t)b * 768 + t];
        if (t < 32) {
            float rt = 0.f;
            for (int nn = 0; nn < 10; ++nn) rt = fmaf(gts[nn][t], swt[nn], rt);
            v += rt;
        }
        fu[t] = v;
    }
    __syncthreads();
    // head layer 1: 800 -> 128 per joint, relu
    {
        int j = t >> 7, h = t & 127;
        const float* wrow = w1 + (size_t)(j * 128 + h) * 800;
        float acc = b1[j * 128 + h];
        const float4* wv4 = (const float4*)wrow;
        const float4* fu4 = (const float4*)fu;
        for (int q = 0; q < 192; ++q) {
            float4 wv = wv4[q];
            float4 xv = fu4[q];
            acc = fmaf(xv.x, wv.x, acc);
            acc = fmaf(xv.y, wv.y, acc);
            acc = fmaf(xv.z, wv.z, acc);
            acc = fmaf(xv.w, wv.w, acc);
        }
        for (int g = 0; g < 32; ++g) acc = fmaf(gts[j][g], wrow[768 + g], acc);
        h1s[j][h] = fmaxf(acc, 0.f);
    }
    __syncthreads();
    // head layer 2: 128 -> 64, relu
    if (t < 384) {
        int j = t >> 6, h = t & 63;
        const float* wrow = w2 + (size_t)(j * 64 + h) * 128;
        float acc = b2[j * 64 + h];
        for (int k = 0; k < 128; ++k) acc = fmaf(h1s[j][k], wrow[k], acc);
        h2s[j][h] = fmaxf(acc, 0.f);
    }
    __syncthreads();
    // head layer 3: 64 -> 16
    if (t < 96) {
        int j = t / 16, oo = t - j * 16;
        const float* wrow = w3 + (size_t)(j * 16 + oo) * 64;
        float acc = b3[j * 16 + oo];
        for (int k = 0; k < 64; ++k) acc = fmaf(h2s[j][k], wrow[k], acc);
        a3[j][oo] = acc;
    }
    __syncthreads();
    // write (B,16,10): out[b][c][jj] = a[b][jj][c] for jj<6 else 0
    if (t < 160) {
        int c = t / 10, jj = t - c * 10;
        out[(size_t)b * 160 + t] = (jj < 6) ? a3[jj][c] : 0.f;
    }
}

// ---------------------------------------------------------------------------
extern "C" void kernel_launch(void* const* d_in, const int* in_sizes, int n_in,
                              void* d_out, int out_size, void* d_ws, size_t ws_size,
                              hipStream_t stream) {
    const float* images = (const float*)d_in[0];
    const int* tlen = (const int*)d_in[1];
    const float* nfeat = (const float*)d_in[2];
    const int* eidx = (const int*)d_in[3];
    const float* conv_w = (const float*)d_in[4];
    const float* conv_b = (const float*)d_in[5];
    const float* fc1w = (const float*)d_in[6];
    const float* fc1b = (const float*)d_in[7];
    const float* fc2w = (const float*)d_in[8];
    const float* fc2b = (const float*)d_in[9];
    const float* temb = (const float*)d_in[10];
    const float* tfw = (const float*)d_in[11];
    const float* tfb = (const float*)d_in[12];
    const float* e1w = (const float*)d_in[13];
    const float* e1b = (const float*)d_in[14];
    const float* e2w = (const float*)d_in[15];
    const float* e2b = (const float*)d_in[16];
    const float* gcw = (const float*)d_in[17];
    const float* gcb = (const float*)d_in[18];
    const float* lns = (const float*)d_in[19];
    const float* lnb = (const float*)d_in[20];
    const float* pjw = (const float*)d_in[21];
    const float* pjb = (const float*)d_in[22];
    const float* a1w = (const float*)d_in[23];
    const float* a1b = (const float*)d_in[24];
    const float* a2w = (const float*)d_in[25];
    const float* a2b = (const float*)d_in[26];
    const float* w1 = (const float*)d_in[27];
    const float* b1 = (const float*)d_in[28];
    const float* w2 = (const float*)d_in[29];
    const float* b2 = (const float*)d_in[30];
    const float* w3 = (const float*)d_in[31];
    const float* b3 = (const float*)d_in[32];

    const int B = in_sizes[0] / (3 * 224 * 224);  // 128

    float* ws = (float*)d_ws;
    float* wT = ws;                                 // 4704
    float* pooled = wT + 4704;                      // B*1568
    float* h1 = pooled + (size_t)B * 1568;          // B*512
    float* vlm = h1 + (size_t)B * 512;              // B*768

    prep_wT<<<1, 256, 0, stream>>>(conv_w, wT);
    conv_pool<<<dim3(2, 7, B), 256, 0, stream>>>(images, wT, conv_b, pooled);
    fc1_k<<<(512 * 16) / 4, 256, 0, stream>>>(pooled, fc1w, fc1b, h1);
    vlm_k<<<(768 * 16) / 4, 256, 0, stream>>>(h1, fc2w, fc2b, tlen, temb, tfw, tfb, vlm);
    graph_head<<<B, 768, 0, stream>>>(nfeat, eidx, e1w, e1b, e2w, e2b, gcw, gcb,
                                      lns, lnb, pjw, pjb, a1w, a1b, a2w, a2b,
                                      w1, b1, w2, b2, w3, b3, vlm, (float*)d_out);
}

// Round 2
// 215.309 us; speedup vs baseline: 1.9883x; 1.9883x over previous
//
#include <hip/hip_runtime.h>
#include <math.h>

typedef __attribute__((ext_vector_type(8))) short bf16x8;
typedef __attribute__((ext_vector_type(4))) float f32x4;

static __device__ __forceinline__ unsigned short f2bf(float f) {
    union { float f; unsigned int u; } x{f};
    unsigned int u = x.u;
    unsigned int r = (u + 0x7fffu + ((u >> 16) & 1u)) >> 16;  // RNE
    return (unsigned short)r;
}

// ---------------------------------------------------------------------------
// Stage 0: weights -> wB[24 slices][32 ch][8 kx] bf16  (slice = c*7+ky, pad)
// ---------------------------------------------------------------------------
__global__ __launch_bounds__(256) void wprep(const float* __restrict__ conv_w,
                                             unsigned short* __restrict__ wB) {
    for (int idx = threadIdx.x; idx < 24 * 32 * 8; idx += 256) {
        int s = idx >> 8;            // slice 0..23
        int ch = (idx >> 3) & 31;
        int kx = idx & 7;
        float v = 0.f;
        if (s < 21 && kx < 7) {
            int c = s / 7, ky = s - c * 7;
            v = conv_w[ch * 147 + c * 49 + ky * 7 + kx];
        }
        wB[idx] = f2bf(v);
    }
}

// ---------------------------------------------------------------------------
// Stage 1: fused conv(7x7,s2,p3)+bias+relu+16x16 avgpool via MFMA 16x16x32.
// grid (py=7, b=B), block 512 (8 waves). Wave w: oy = 16*py + {2w, 2w+1}.
// Per oy: 7 tiles of 16 ox (one pooling column each) x 32 ch.
// A-frag: 8 contiguous bf16 pixels (kx 0..7) -> 4 dword-aligned LDS reads.
// ---------------------------------------------------------------------------
__global__ __launch_bounds__(512) void conv_mfma(const float* __restrict__ img,
                                                 const unsigned int* __restrict__ wBu,
                                                 const float* __restrict__ cb,
                                                 float* __restrict__ pooled) {
    __shared__ unsigned int patch[111 * 116];  // [c*37+pr][dword col], bf16x2
    __shared__ float swave[8][7][32];
    const int t = threadIdx.x;
    const int py = blockIdx.x, b = blockIdx.y;
    const int lane = t & 63, wid = t >> 6;
    const int r16 = lane & 15, g = lane >> 4;  // A row, k-group

    // ---- stage image patch as bf16 (rows iy = 32py-3+pr, cols ix=-3..228) --
    const float* ib = img + (size_t)b * 3 * 224 * 224;
    for (int idx = t; idx < 111 * 116; idx += 512) {
        int row = idx / 116;
        int dc = idx - row * 116;
        int c = row / 37, pr = row - c * 37;
        int iy = 32 * py - 3 + pr;
        int ix0 = 2 * dc - 3;
        float f0 = 0.f, f1 = 0.f;
        if ((unsigned)iy < 224u) {
            const float* rp = ib + (c * 224 + iy) * 224;
            if ((unsigned)ix0 < 224u) f0 = rp[ix0];
            if ((unsigned)(ix0 + 1) < 224u) f1 = rp[ix0 + 1];
        }
        patch[idx] = (unsigned int)f2bf(f0) | ((unsigned int)f2bf(f1) << 16);
    }

    // ---- preload B fragments (weights) : 2 ch-halves x 6 ksteps ----------
    bf16x8 bfrA[6], bfrB[6];
    int rowoff[6];
#pragma unroll
    for (int k = 0; k < 6; ++k) {
        int s = 4 * k + g;
        int sc = s > 20 ? 20 : s;
        int c = sc / 7, ky = sc - c * 7;
        rowoff[k] = c * 37 + ky;
        union { unsigned int u[4]; bf16x8 v; } ua, ub;
#pragma unroll
        for (int w = 0; w < 4; ++w) {
            ua.u[w] = wBu[(s * 32 + r16) * 4 + w];
            ub.u[w] = wBu[(s * 32 + r16 + 16) * 4 + w];
        }
        bfrA[k] = ua.v;
        bfrB[k] = ub.v;
    }
    const float biasA = cb[r16], biasB = cb[r16 + 16];

    __syncthreads();

    // ---- main loop: 2 oy x 7 tiles, MFMA + fused relu-pool ---------------
    float accA[7], accB[7];
#pragma unroll
    for (int p = 0; p < 7; ++p) accA[p] = accB[p] = 0.f;

    for (int q = 0; q < 2; ++q) {
        const int oyl = 2 * wid + q;  // 0..15
        int rb[6];
#pragma unroll
        for (int k = 0; k < 6; ++k) rb[k] = (rowoff[k] + 2 * oyl) * 116;

        for (int t7 = 0; t7 < 7; ++t7) {
            const int oxr = 16 * t7 + r16;  // this lane's position (<=111)
            f32x4 C0 = {0.f, 0.f, 0.f, 0.f}, C1 = {0.f, 0.f, 0.f, 0.f};
#pragma unroll
            for (int k = 0; k < 6; ++k) {
                const unsigned int* ap = &patch[rb[k] + oxr];
                union { unsigned int u[4]; bf16x8 v; } ua;
                ua.u[0] = ap[0];
                ua.u[1] = ap[1];
                ua.u[2] = ap[2];
                ua.u[3] = ap[3];
                C0 = __builtin_amdgcn_mfma_f32_16x16x32_bf16(ua.v, bfrA[k], C0, 0, 0, 0);
                C1 = __builtin_amdgcn_mfma_f32_16x16x32_bf16(ua.v, bfrB[k], C1, 0, 0, 0);
            }
            float s0 = 0.f, s1 = 0.f;
#pragma unroll
            for (int reg = 0; reg < 4; ++reg) {
                s0 += fmaxf(C0[reg] + biasA, 0.f);
                s1 += fmaxf(C1[reg] + biasB, 0.f);
            }
            accA[t7] += s0;
            accB[t7] += s1;
        }
    }
    // reduce over the 4 lane-groups sharing each channel
#pragma unroll
    for (int p = 0; p < 7; ++p) {
        accA[p] += __shfl_xor(accA[p], 16);
        accA[p] += __shfl_xor(accA[p], 32);
        accB[p] += __shfl_xor(accB[p], 16);
        accB[p] += __shfl_xor(accB[p], 32);
    }
    if (lane < 16) {
#pragma unroll
        for (int p = 0; p < 7; ++p) {
            swave[wid][p][lane] = accA[p];
            swave[wid][p][lane + 16] = accB[p];
        }
    }
    __syncthreads();
    // ---- combine 8 waves (each owns 2 oy rows) and write pooled ----------
    if (t < 224) {
        int p = t >> 5, ch = t & 31;
        float s = 0.f;
#pragma unroll
        for (int w = 0; w < 8; ++w) s += swave[w][p][ch];
        pooled[(size_t)b * 1568 + ch * 49 + py * 7 + p] = s * (1.f / 256.f);
    }
}

// ---------------------------------------------------------------------------
// Stage 2: fc1  (B,1568)->(B,512), relu. wave per (output, 8-batch group)
// ---------------------------------------------------------------------------
__global__ __launch_bounds__(256) void fc1_k(const float* __restrict__ in,
                                             const float* __restrict__ w,
                                             const float* __restrict__ bias,
                                             float* __restrict__ out) {
    int gw = (blockIdx.x * 256 + threadIdx.x) >> 6;
    int lane = threadIdx.x & 63;
    int o = gw >> 4;          // 512 outputs
    int b0 = (gw & 15) * 8;   // batch group
    float acc[8] = {0, 0, 0, 0, 0, 0, 0, 0};
    const float4* wr = (const float4*)(w + (size_t)o * 1568);
    for (int i = lane; i < 392; i += 64) {
        float4 wv = wr[i];
#pragma unroll
        for (int j = 0; j < 8; ++j) {
            float4 xv = *(const float4*)(in + (size_t)(b0 + j) * 1568 + i * 4);
            acc[j] = fmaf(xv.x, wv.x, acc[j]);
            acc[j] = fmaf(xv.y, wv.y, acc[j]);
            acc[j] = fmaf(xv.z, wv.z, acc[j]);
            acc[j] = fmaf(xv.w, wv.w, acc[j]);
        }
    }
#pragma unroll
    for (int j = 0; j < 8; ++j) {
        acc[j] += __shfl_xor(acc[j], 32);
        acc[j] += __shfl_xor(acc[j], 16);
        acc[j] += __shfl_xor(acc[j], 8);
        acc[j] += __shfl_xor(acc[j], 4);
        acc[j] += __shfl_xor(acc[j], 2);
        acc[j] += __shfl_xor(acc[j], 1);
    }
    float v = 0.f;
#pragma unroll
    for (int j = 0; j < 8; ++j)
        if (lane == j) v = acc[j];
    if (lane < 8) out[(size_t)(b0 + lane) * 512 + o] = fmaxf(v + bias[o], 0.f);
}

// ---------------------------------------------------------------------------
// Stage 3: vlm = img_fc2(h1) + text_fc(text_emb[len]) + biases  -> (B,768)
// ---------------------------------------------------------------------------
__global__ __launch_bounds__(256) void vlm_k(const float* __restrict__ h1,
                                             const float* __restrict__ w2,
                                             const float* __restrict__ b2,
                                             const int* __restrict__ tlen,
                                             const float* __restrict__ temb,
                                             const float* __restrict__ tw,
                                             const float* __restrict__ tb,
                                             float* __restrict__ vlm) {
    int gw = (blockIdx.x * 256 + threadIdx.x) >> 6;
    int lane = threadIdx.x & 63;
    int o = gw >> 4;          // 768 outputs
    int b0 = (gw & 15) * 8;
    int rows[8];
#pragma unroll
    for (int j = 0; j < 8; ++j) {
        int r = tlen[b0 + j];
        rows[j] = min(max(r, 0), 9999);
    }
    float acc[8] = {0, 0, 0, 0, 0, 0, 0, 0};
    const float4* wr = (const float4*)(w2 + (size_t)o * 512);
    for (int i = lane; i < 128; i += 64) {
        float4 wv = wr[i];
#pragma unroll
        for (int j = 0; j < 8; ++j) {
            float4 xv = *(const float4*)(h1 + (size_t)(b0 + j) * 512 + i * 4);
            acc[j] = fmaf(xv.x, wv.x, acc[j]);
            acc[j] = fmaf(xv.y, wv.y, acc[j]);
            acc[j] = fmaf(xv.z, wv.z, acc[j]);
            acc[j] = fmaf(xv.w, wv.w, acc[j]);
        }
    }
    {
        const float4* wt4 = (const float4*)(tw + (size_t)o * 256);
        int i = lane;  // 64 chunks exactly
        float4 wv = wt4[i];
#pragma unroll
        for (int j = 0; j < 8; ++j) {
            float4 xv = *(const float4*)(temb + (size_t)rows[j] * 256 + i * 4);
            acc[j] = fmaf(xv.x, wv.x, acc[j]);
            acc[j] = fmaf(xv.y, wv.y, acc[j]);
            acc[j] = fmaf(xv.z, wv.z, acc[j]);
            acc[j] = fmaf(xv.w, wv.w, acc[j]);
        }
    }
#pragma unroll
    for (int j = 0; j < 8; ++j) {
        acc[j] += __shfl_xor(acc[j], 32);
        acc[j] += __shfl_xor(acc[j], 16);
        acc[j] += __shfl_xor(acc[j], 8);
        acc[j] += __shfl_xor(acc[j], 4);
        acc[j] += __shfl_xor(acc[j], 2);
        acc[j] += __shfl_xor(acc[j], 1);
    }
    float v = 0.f;
#pragma unroll
    for (int j = 0; j < 8; ++j)
        if (lane == j) v = acc[j];
    if (lane < 8) vlm[(size_t)(b0 + lane) * 768 + o] = v + b2[o] + tb[o];
}

// ---------------------------------------------------------------------------
// Stage 4: whole graph branch + attention pooling + fused token + heads
// ---------------------------------------------------------------------------
__global__ __launch_bounds__(768) void graph_head(
    const float* __restrict__ nfeat, const int* __restrict__ eidx,
    const float* __restrict__ e1w, const float* __restrict__ e1b,
    const float* __restrict__ e2w, const float* __restrict__ e2b,
    const float* __restrict__ gcw, const float* __restrict__ gcb,
    const float* __restrict__ lns, const float* __restrict__ lnb,
    const float* __restrict__ pjw, const float* __restrict__ pjb,
    const float* __restrict__ a1w, const float* __restrict__ a1b,
    const float* __restrict__ a2w, const float* __restrict__ a2b,
    const float* __restrict__ w1, const float* __restrict__ b1,
    const float* __restrict__ w2, const float* __restrict__ b2,
    const float* __restrict__ w3, const float* __restrict__ b3,
    const float* __restrict__ vlm, float* __restrict__ out) {
    __shared__ float nf[10][20];
    __shared__ float hx[10][64];
    __shared__ float xs[10][64];
    __shared__ float nb[10][64];
    __shared__ int se[18], de[18];
    __shared__ float gts[10][32];
    __shared__ __align__(16) float fu[768];
    __shared__ float h1s[6][128];
    __shared__ float h2s[6][64];
    __shared__ float a3[6][16];
    __shared__ float sv[10], swt[10];
    const int t = threadIdx.x;
    const int b = blockIdx.x;

    if (t < 190) {
        int n = t / 19, i = t - n * 19;
        nf[n][i] = nfeat[(size_t)(b * 10 + n) * 19 + i];
    }
    if (t < 36) {
        if (t < 18) se[t] = eidx[b * 36 + t];
        else de[t - 18] = eidx[b * 36 + t];
    }
    __syncthreads();

    const int n = t >> 6, o = t & 63;
    if (t < 640) {
        float acc = e1b[o];
#pragma unroll
        for (int i = 0; i < 19; ++i) acc = fmaf(nf[n][i], e1w[o * 19 + i], acc);
        hx[n][o] = fmaxf(acc, 0.f);
    }
    __syncthreads();
    if (t < 640) {
        float acc = e2b[o];
        for (int k = 0; k < 64; ++k) acc = fmaf(hx[n][k], e2w[o * 64 + k], acc);
        xs[n][o] = acc;
    }
    __syncthreads();

    for (int l = 0; l < 3; ++l) {
        if (t < 640) {
            float s = 0.f;
            int cnt = 0;
            for (int e = 0; e < 18; ++e) {
                if (de[e] == n) {
                    s += xs[se[e]][o];
                    cnt++;
                }
            }
            nb[n][o] = s / (float)(cnt > 1 ? cnt : 1);
        }
        __syncthreads();
        float xn = 0.f;
        if (t < 640) {
            const float* wrow = gcw + (size_t)(l * 64 + o) * 128;
            float v = gcb[l * 64 + o];
            for (int k = 0; k < 64; ++k) v = fmaf(xs[n][k], wrow[k], v);
            for (int k = 0; k < 64; ++k) v = fmaf(nb[n][k], wrow[64 + k], v);
            v += xs[n][o];
            float mu = v;
            mu += __shfl_xor(mu, 32);
            mu += __shfl_xor(mu, 16);
            mu += __shfl_xor(mu, 8);
            mu += __shfl_xor(mu, 4);
            mu += __shfl_xor(mu, 2);
            mu += __shfl_xor(mu, 1);
            mu *= (1.f / 64.f);
            float d = v - mu;
            float vr = d * d;
            vr += __shfl_xor(vr, 32);
            vr += __shfl_xor(vr, 16);
            vr += __shfl_xor(vr, 8);
            vr += __shfl_xor(vr, 4);
            vr += __shfl_xor(vr, 2);
            vr += __shfl_xor(vr, 1);
            vr *= (1.f / 64.f);
            xn = fmaxf(d / sqrtf(vr + 1e-5f) * lns[l * 64 + o] + lnb[l * 64 + o], 0.f);
        }
        __syncthreads();
        if (t < 640) xs[n][o] = xn;
        __syncthreads();
    }

    if (t < 320) {
        int nn = t >> 5, j = t & 31;
        float g = pjb[j];
        for (int k = 0; k < 64; ++k) g = fmaf(xs[nn][k], pjw[j * 64 + k], g);
        gts[nn][j] = g;
    }
    __syncthreads();
    if (t < 10) {
        float s = a2b[0];
        for (int h = 0; h < 16; ++h) {
            float z = a1b[h];
            for (int k = 0; k < 32; ++k) z = fmaf(gts[t][k], a1w[h * 32 + k], z);
            s = fmaf(tanhf(z), a2w[h], s);
        }
        sv[t] = s;
    }
    __syncthreads();
    if (t == 0) {
        float m = sv[0];
        for (int i = 1; i < 10; ++i) m = fmaxf(m, sv[i]);
        float sum = 0.f;
        float e[10];
        for (int i = 0; i < 10; ++i) {
            e[i] = expf(sv[i] - m);
            sum += e[i];
        }
        for (int i = 0; i < 10; ++i) swt[i] = e[i] / sum;
    }
    __syncthreads();
    {
        float v = vlm[(size_t)b * 768 + t];
        if (t < 32) {
            float rt = 0.f;
            for (int nn = 0; nn < 10; ++nn) rt = fmaf(gts[nn][t], swt[nn], rt);
            v += rt;
        }
        fu[t] = v;
    }
    __syncthreads();
    {
        int j = t >> 7, h = t & 127;
        const float* wrow = w1 + (size_t)(j * 128 + h) * 800;
        float acc = b1[j * 128 + h];
        const float4* wv4 = (const float4*)wrow;
        const float4* fu4 = (const float4*)fu;
        for (int q = 0; q < 192; ++q) {
            float4 wv = wv4[q];
            float4 xv = fu4[q];
            acc = fmaf(xv.x, wv.x, acc);
            acc = fmaf(xv.y, wv.y, acc);
            acc = fmaf(xv.z, wv.z, acc);
            acc = fmaf(xv.w, wv.w, acc);
        }
        for (int g = 0; g < 32; ++g) acc = fmaf(gts[j][g], wrow[768 + g], acc);
        h1s[j][h] = fmaxf(acc, 0.f);
    }
    __syncthreads();
    if (t < 384) {
        int j = t >> 6, h = t & 63;
        const float* wrow = w2 + (size_t)(j * 64 + h) * 128;
        float acc = b2[j * 64 + h];
        for (int k = 0; k < 128; ++k) acc = fmaf(h1s[j][k], wrow[k], acc);
        h2s[j][h] = fmaxf(acc, 0.f);
    }
    __syncthreads();
    if (t < 96) {
        int j = t / 16, oo = t - j * 16;
        const float* wrow = w3 + (size_t)(j * 16 + oo) * 64;
        float acc = b3[j * 16 + oo];
        for (int k = 0; k < 64; ++k) acc = fmaf(h2s[j][k], wrow[k], acc);
        a3[j][oo] = acc;
    }
    __syncthreads();
    if (t < 160) {
        int c = t / 10, jj = t - c * 10;
        out[(size_t)b * 160 + t] = (jj < 6) ? a3[jj][c] : 0.f;
    }
}

// ---------------------------------------------------------------------------
extern "C" void kernel_launch(void* const* d_in, const int* in_sizes, int n_in,
                              void* d_out, int out_size, void* d_ws, size_t ws_size,
                              hipStream_t stream) {
    const float* images = (const float*)d_in[0];
    const int* tlen = (const int*)d_in[1];
    const float* nfeat = (const float*)d_in[2];
    const int* eidx = (const int*)d_in[3];
    const float* conv_w = (const float*)d_in[4];
    const float* conv_b = (const float*)d_in[5];
    const float* fc1w = (const float*)d_in[6];
    const float* fc1b = (const float*)d_in[7];
    const float* fc2w = (const float*)d_in[8];
    const float* fc2b = (const float*)d_in[9];
    const float* temb = (const float*)d_in[10];
    const float* tfw = (const float*)d_in[11];
    const float* tfb = (const float*)d_in[12];
    const float* e1w = (const float*)d_in[13];
    const float* e1b = (const float*)d_in[14];
    const float* e2w = (const float*)d_in[15];
    const float* e2b = (const float*)d_in[16];
    const float* gcw = (const float*)d_in[17];
    const float* gcb = (const float*)d_in[18];
    const float* lns = (const float*)d_in[19];
    const float* lnb = (const float*)d_in[20];
    const float* pjw = (const float*)d_in[21];
    const float* pjb = (const float*)d_in[22];
    const float* a1w = (const float*)d_in[23];
    const float* a1b = (const float*)d_in[24];
    const float* a2w = (const float*)d_in[25];
    const float* a2b = (const float*)d_in[26];
    const float* w1 = (const float*)d_in[27];
    const float* b1 = (const float*)d_in[28];
    const float* w2 = (const float*)d_in[29];
    const float* b2 = (const float*)d_in[30];
    const float* w3 = (const float*)d_in[31];
    const float* b3 = (const float*)d_in[32];

    const int B = in_sizes[0] / (3 * 224 * 224);  // 128

    float* ws = (float*)d_ws;
    unsigned short* wB = (unsigned short*)d_ws;     // 6144 ushorts (=3072 floats)
    float* pooled = ws + 3072;                      // B*1568
    float* h1 = pooled + (size_t)B * 1568;          // B*512
    float* vlm = h1 + (size_t)B * 512;              // B*768

    wprep<<<1, 256, 0, stream>>>(conv_w, wB);
    conv_mfma<<<dim3(7, B), 512, 0, stream>>>(images, (const unsigned int*)wB,
                                              conv_b, pooled);
    fc1_k<<<(512 * 16) / 4, 256, 0, stream>>>(pooled, fc1w, fc1b, h1);
    vlm_k<<<(768 * 16) / 4, 256, 0, stream>>>(h1, fc2w, fc2b, tlen, temb, tfw, tfb, vlm);
    graph_head<<<B, 768, 0, stream>>>(nfeat, eidx, e1w, e1b, e2w, e2b, gcw, gcb,
                                      lns, lnb, pjw, pjb, a1w, a1b, a2w, a2b,
                                      w1, b1, w2, b2, w3, b3, vlm, (float*)d_out);
}

// Round 3
// 164.803 us; speedup vs baseline: 2.5976x; 1.3065x over previous
//
#include <hip/hip_runtime.h>
#include <math.h>

typedef __attribute__((ext_vector_type(8))) short bf16x8;
typedef __attribute__((ext_vector_type(4))) float f32x4;

static __device__ __forceinline__ unsigned short f2bf(float f) {
    union { float f; unsigned int u; } x{f};
    unsigned int u = x.u;
    unsigned int r = (u + 0x7fffu + ((u >> 16) & 1u)) >> 16;  // RNE
    return (unsigned short)r;
}

// ---------------------------------------------------------------------------
// Stage 0: weights -> wB[24 slices][32 ch][8 kx] bf16  (slice = c*7+ky, pad)
// ---------------------------------------------------------------------------
__global__ __launch_bounds__(256) void wprep(const float* __restrict__ conv_w,
                                             unsigned short* __restrict__ wB) {
    for (int idx = threadIdx.x; idx < 24 * 32 * 8; idx += 256) {
        int s = idx >> 8;
        int ch = (idx >> 3) & 31;
        int kx = idx & 7;
        float v = 0.f;
        if (s < 21 && kx < 7) {
            int c = s / 7, ky = s - c * 7;
            v = conv_w[ch * 147 + c * 49 + ky * 7 + kx];
        }
        wB[idx] = f2bf(v);
    }
}

// ---------------------------------------------------------------------------
// Stage 1: fused conv(7x7,s2,p3)+bias+relu+16x16 avgpool via MFMA 16x16x32.
// ---------------------------------------------------------------------------
__global__ __launch_bounds__(512) void conv_mfma(const float* __restrict__ img,
                                                 const unsigned int* __restrict__ wBu,
                                                 const float* __restrict__ cb,
                                                 float* __restrict__ pooled) {
    __shared__ unsigned int patch[111 * 116];  // [c*37+pr][dword col], bf16x2
    __shared__ float swave[8][7][32];
    const int t = threadIdx.x;
    const int py = blockIdx.x, b = blockIdx.y;
    const int lane = t & 63, wid = t >> 6;
    const int r16 = lane & 15, g = lane >> 4;

    const float* ib = img + (size_t)b * 3 * 224 * 224;
    for (int idx = t; idx < 111 * 116; idx += 512) {
        int row = idx / 116;
        int dc = idx - row * 116;
        int c = row / 37, pr = row - c * 37;
        int iy = 32 * py - 3 + pr;
        int ix0 = 2 * dc - 3;
        float f0 = 0.f, f1 = 0.f;
        if ((unsigned)iy < 224u) {
            const float* rp = ib + (c * 224 + iy) * 224;
            if ((unsigned)ix0 < 224u) f0 = rp[ix0];
            if ((unsigned)(ix0 + 1) < 224u) f1 = rp[ix0 + 1];
        }
        patch[idx] = (unsigned int)f2bf(f0) | ((unsigned int)f2bf(f1) << 16);
    }

    bf16x8 bfrA[6], bfrB[6];
    int rowoff[6];
#pragma unroll
    for (int k = 0; k < 6; ++k) {
        int s = 4 * k + g;
        int sc = s > 20 ? 20 : s;
        int c = sc / 7, ky = sc - c * 7;
        rowoff[k] = c * 37 + ky;
        union { unsigned int u[4]; bf16x8 v; } ua, ub;
#pragma unroll
        for (int w = 0; w < 4; ++w) {
            ua.u[w] = wBu[(s * 32 + r16) * 4 + w];
            ub.u[w] = wBu[(s * 32 + r16 + 16) * 4 + w];
        }
        bfrA[k] = ua.v;
        bfrB[k] = ub.v;
    }
    const float biasA = cb[r16], biasB = cb[r16 + 16];

    __syncthreads();

    float accA[7], accB[7];
#pragma unroll
    for (int p = 0; p < 7; ++p) accA[p] = accB[p] = 0.f;

    for (int q = 0; q < 2; ++q) {
        const int oyl = 2 * wid + q;
        int rb[6];
#pragma unroll
        for (int k = 0; k < 6; ++k) rb[k] = (rowoff[k] + 2 * oyl) * 116;

        for (int t7 = 0; t7 < 7; ++t7) {
            const int oxr = 16 * t7 + r16;
            f32x4 C0 = {0.f, 0.f, 0.f, 0.f}, C1 = {0.f, 0.f, 0.f, 0.f};
#pragma unroll
            for (int k = 0; k < 6; ++k) {
                const unsigned int* ap = &patch[rb[k] + oxr];
                union { unsigned int u[4]; bf16x8 v; } ua;
                ua.u[0] = ap[0];
                ua.u[1] = ap[1];
                ua.u[2] = ap[2];
                ua.u[3] = ap[3];
                C0 = __builtin_amdgcn_mfma_f32_16x16x32_bf16(ua.v, bfrA[k], C0, 0, 0, 0);
                C1 = __builtin_amdgcn_mfma_f32_16x16x32_bf16(ua.v, bfrB[k], C1, 0, 0, 0);
            }
            float s0 = 0.f, s1 = 0.f;
#pragma unroll
            for (int reg = 0; reg < 4; ++reg) {
                s0 += fmaxf(C0[reg] + biasA, 0.f);
                s1 += fmaxf(C1[reg] + biasB, 0.f);
            }
            accA[t7] += s0;
            accB[t7] += s1;
        }
    }
#pragma unroll
    for (int p = 0; p < 7; ++p) {
        accA[p] += __shfl_xor(accA[p], 16);
        accA[p] += __shfl_xor(accA[p], 32);
        accB[p] += __shfl_xor(accB[p], 16);
        accB[p] += __shfl_xor(accB[p], 32);
    }
    if (lane < 16) {
#pragma unroll
        for (int p = 0; p < 7; ++p) {
            swave[wid][p][lane] = accA[p];
            swave[wid][p][lane + 16] = accB[p];
        }
    }
    __syncthreads();
    if (t < 224) {
        int p = t >> 5, ch = t & 31;
        float s = 0.f;
#pragma unroll
        for (int w = 0; w < 8; ++w) s += swave[w][p][ch];
        pooled[(size_t)b * 1568 + ch * 49 + py * 7 + p] = s * (1.f / 256.f);
    }
}

// ---------------------------------------------------------------------------
// Stage 2: fc1  (B,1568)->(B,512), relu
// ---------------------------------------------------------------------------
__global__ __launch_bounds__(256) void fc1_k(const float* __restrict__ in,
                                             const float* __restrict__ w,
                                             const float* __restrict__ bias,
                                             float* __restrict__ out) {
    int gw = (blockIdx.x * 256 + threadIdx.x) >> 6;
    int lane = threadIdx.x & 63;
    int o = gw >> 4;
    int b0 = (gw & 15) * 8;
    float acc[8] = {0, 0, 0, 0, 0, 0, 0, 0};
    const float4* wr = (const float4*)(w + (size_t)o * 1568);
    for (int i = lane; i < 392; i += 64) {
        float4 wv = wr[i];
#pragma unroll
        for (int j = 0; j < 8; ++j) {
            float4 xv = *(const float4*)(in + (size_t)(b0 + j) * 1568 + i * 4);
            acc[j] = fmaf(xv.x, wv.x, acc[j]);
            acc[j] = fmaf(xv.y, wv.y, acc[j]);
            acc[j] = fmaf(xv.z, wv.z, acc[j]);
            acc[j] = fmaf(xv.w, wv.w, acc[j]);
        }
    }
#pragma unroll
    for (int j = 0; j < 8; ++j) {
        acc[j] += __shfl_xor(acc[j], 32);
        acc[j] += __shfl_xor(acc[j], 16);
        acc[j] += __shfl_xor(acc[j], 8);
        acc[j] += __shfl_xor(acc[j], 4);
        acc[j] += __shfl_xor(acc[j], 2);
        acc[j] += __shfl_xor(acc[j], 1);
    }
    float v = 0.f;
#pragma unroll
    for (int j = 0; j < 8; ++j)
        if (lane == j) v = acc[j];
    if (lane < 8) out[(size_t)(b0 + lane) * 512 + o] = fmaxf(v + bias[o], 0.f);
}

// ---------------------------------------------------------------------------
// Stage 3: vlm = img_fc2(h1) + text_fc(text_emb[len]) + biases
// ---------------------------------------------------------------------------
__global__ __launch_bounds__(256) void vlm_k(const float* __restrict__ h1,
                                             const float* __restrict__ w2,
                                             const float* __restrict__ b2,
                                             const int* __restrict__ tlen,
                                             const float* __restrict__ temb,
                                             const float* __restrict__ tw,
                                             const float* __restrict__ tb,
                                             float* __restrict__ vlm) {
    int gw = (blockIdx.x * 256 + threadIdx.x) >> 6;
    int lane = threadIdx.x & 63;
    int o = gw >> 4;
    int b0 = (gw & 15) * 8;
    int rows[8];
#pragma unroll
    for (int j = 0; j < 8; ++j) {
        int r = tlen[b0 + j];
        rows[j] = min(max(r, 0), 9999);
    }
    float acc[8] = {0, 0, 0, 0, 0, 0, 0, 0};
    const float4* wr = (const float4*)(w2 + (size_t)o * 512);
    for (int i = lane; i < 128; i += 64) {
        float4 wv = wr[i];
#pragma unroll
        for (int j = 0; j < 8; ++j) {
            float4 xv = *(const float4*)(h1 + (size_t)(b0 + j) * 512 + i * 4);
            acc[j] = fmaf(xv.x, wv.x, acc[j]);
            acc[j] = fmaf(xv.y, wv.y, acc[j]);
            acc[j] = fmaf(xv.z, wv.z, acc[j]);
            acc[j] = fmaf(xv.w, wv.w, acc[j]);
        }
    }
    {
        const float4* wt4 = (const float4*)(tw + (size_t)o * 256);
        int i = lane;
        float4 wv = wt4[i];
#pragma unroll
        for (int j = 0; j < 8; ++j) {
            float4 xv = *(const float4*)(temb + (size_t)rows[j] * 256 + i * 4);
            acc[j] = fmaf(xv.x, wv.x, acc[j]);
            acc[j] = fmaf(xv.y, wv.y, acc[j]);
            acc[j] = fmaf(xv.z, wv.z, acc[j]);
            acc[j] = fmaf(xv.w, wv.w, acc[j]);
        }
    }
#pragma unroll
    for (int j = 0; j < 8; ++j) {
        acc[j] += __shfl_xor(acc[j], 32);
        acc[j] += __shfl_xor(acc[j], 16);
        acc[j] += __shfl_xor(acc[j], 8);
        acc[j] += __shfl_xor(acc[j], 4);
        acc[j] += __shfl_xor(acc[j], 2);
        acc[j] += __shfl_xor(acc[j], 1);
    }
    float v = 0.f;
#pragma unroll
    for (int j = 0; j < 8; ++j)
        if (lane == j) v = acc[j];
    if (lane < 8) vlm[(size_t)(b0 + lane) * 768 + o] = v + b2[o] + tb[o];
}

// ---------------------------------------------------------------------------
// Stage 4a: graph branch -> fused[B][768], gts[B][10][32]
// ---------------------------------------------------------------------------
__global__ __launch_bounds__(768) void graph_k(
    const float* __restrict__ nfeat, const int* __restrict__ eidx,
    const float* __restrict__ e1w, const float* __restrict__ e1b,
    const float* __restrict__ e2w, const float* __restrict__ e2b,
    const float* __restrict__ gcw, const float* __restrict__ gcb,
    const float* __restrict__ lns, const float* __restrict__ lnb,
    const float* __restrict__ pjw, const float* __restrict__ pjb,
    const float* __restrict__ a1w, const float* __restrict__ a1b,
    const float* __restrict__ a2w, const float* __restrict__ a2b,
    const float* __restrict__ vlm, float* __restrict__ fused_g,
    float* __restrict__ gts_g) {
    __shared__ float nf[10][20];
    __shared__ float hx[10][64];
    __shared__ float xs[10][64];
    __shared__ float nb[10][64];
    __shared__ int se[18], de[18];
    __shared__ float gts[10][32];
    __shared__ float sv[10], swt[10];
    const int t = threadIdx.x;
    const int b = blockIdx.x;

    if (t < 190) {
        int n = t / 19, i = t - n * 19;
        nf[n][i] = nfeat[(size_t)(b * 10 + n) * 19 + i];
    }
    if (t < 36) {
        if (t < 18) se[t] = eidx[b * 36 + t];
        else de[t - 18] = eidx[b * 36 + t];
    }
    __syncthreads();

    const int n = t >> 6, o = t & 63;
    if (t < 640) {
        float acc = e1b[o];
#pragma unroll
        for (int i = 0; i < 19; ++i) acc = fmaf(nf[n][i], e1w[o * 19 + i], acc);
        hx[n][o] = fmaxf(acc, 0.f);
    }
    __syncthreads();
    if (t < 640) {
        float acc = e2b[o];
        for (int k = 0; k < 64; ++k) acc = fmaf(hx[n][k], e2w[o * 64 + k], acc);
        xs[n][o] = acc;
    }
    __syncthreads();

    for (int l = 0; l < 3; ++l) {
        if (t < 640) {
            float s = 0.f;
            int cnt = 0;
            for (int e = 0; e < 18; ++e) {
                if (de[e] == n) {
                    s += xs[se[e]][o];
                    cnt++;
                }
            }
            nb[n][o] = s / (float)(cnt > 1 ? cnt : 1);
        }
        __syncthreads();
        float xn = 0.f;
        if (t < 640) {
            const float* wrow = gcw + (size_t)(l * 64 + o) * 128;
            float v = gcb[l * 64 + o];
            for (int k = 0; k < 64; ++k) v = fmaf(xs[n][k], wrow[k], v);
            for (int k = 0; k < 64; ++k) v = fmaf(nb[n][k], wrow[64 + k], v);
            v += xs[n][o];
            float mu = v;
            mu += __shfl_xor(mu, 32);
            mu += __shfl_xor(mu, 16);
            mu += __shfl_xor(mu, 8);
            mu += __shfl_xor(mu, 4);
            mu += __shfl_xor(mu, 2);
            mu += __shfl_xor(mu, 1);
            mu *= (1.f / 64.f);
            float d = v - mu;
            float vr = d * d;
            vr += __shfl_xor(vr, 32);
            vr += __shfl_xor(vr, 16);
            vr += __shfl_xor(vr, 8);
            vr += __shfl_xor(vr, 4);
            vr += __shfl_xor(vr, 2);
            vr += __shfl_xor(vr, 1);
            vr *= (1.f / 64.f);
            xn = fmaxf(d / sqrtf(vr + 1e-5f) * lns[l * 64 + o] + lnb[l * 64 + o], 0.f);
        }
        __syncthreads();
        if (t < 640) xs[n][o] = xn;
        __syncthreads();
    }

    if (t < 320) {
        int nn = t >> 5, jd = t & 31;
        float g = pjb[jd];
        for (int k = 0; k < 64; ++k) g = fmaf(xs[nn][k], pjw[jd * 64 + k], g);
        gts[nn][jd] = g;
        gts_g[(size_t)b * 320 + t] = g;
    }
    __syncthreads();
    if (t < 10) {
        float s = a2b[0];
        for (int h = 0; h < 16; ++h) {
            float z = a1b[h];
            for (int k = 0; k < 32; ++k) z = fmaf(gts[t][k], a1w[h * 32 + k], z);
            s = fmaf(tanhf(z), a2w[h], s);
        }
        sv[t] = s;
    }
    __syncthreads();
    if (t == 0) {
        float m = sv[0];
        for (int i = 1; i < 10; ++i) m = fmaxf(m, sv[i]);
        float sum = 0.f;
        float e[10];
        for (int i = 0; i < 10; ++i) {
            e[i] = expf(sv[i] - m);
            sum += e[i];
        }
        for (int i = 0; i < 10; ++i) swt[i] = e[i] / sum;
    }
    __syncthreads();
    {
        float v = vlm[(size_t)b * 768 + t];
        if (t < 32) {
            float rt = 0.f;
            for (int nn = 0; nn < 10; ++nn) rt = fmaf(gts[nn][t], swt[nn], rt);
            v += rt;
        }
        fused_g[(size_t)b * 768 + t] = v;
    }
}

// ---------------------------------------------------------------------------
// Stage 4b: head layer 1: comb(800) -> 768 outputs (6 joints x 128), relu.
// block = 4 waves = 4 consecutive o, shared 8-batch group staged in LDS.
// writes h1T[o][b] (transposed for coalesced layer-2 reads).
// ---------------------------------------------------------------------------
__global__ __launch_bounds__(256) void head1_k(const float* __restrict__ fused,
                                               const float* __restrict__ gts,
                                               const float* __restrict__ w1,
                                               const float* __restrict__ b1,
                                               float* __restrict__ h1T) {
    __shared__ __align__(16) float xsm[8][800];
    const int t = threadIdx.x;
    const int ob = blockIdx.x % 192;      // o-quad
    const int bg = blockIdx.x / 192;      // batch group
    const int b0 = bg * 8;
    const int j = ob >> 5;                // joint
    const int lane = t & 63, wid = t >> 6;

    for (int u = t; u < 1600; u += 256) {
        int row = u / 200, i = u - row * 200;
        float4 v;
        if (i < 192)
            v = *(const float4*)(fused + (size_t)(b0 + row) * 768 + i * 4);
        else
            v = *(const float4*)(gts + (size_t)(b0 + row) * 320 + j * 32 + (i - 192) * 4);
        *(float4*)&xsm[row][i * 4] = v;
    }
    __syncthreads();

    const int o = ob * 4 + wid;
    const float4* wr = (const float4*)(w1 + (size_t)o * 800);
    float acc[8] = {0, 0, 0, 0, 0, 0, 0, 0};
    for (int i = lane; i < 200; i += 64) {
        float4 wv = wr[i];
#pragma unroll
        for (int r = 0; r < 8; ++r) {
            float4 xv = *(const float4*)&xsm[r][i * 4];
            acc[r] = fmaf(xv.x, wv.x, acc[r]);
            acc[r] = fmaf(xv.y, wv.y, acc[r]);
            acc[r] = fmaf(xv.z, wv.z, acc[r]);
            acc[r] = fmaf(xv.w, wv.w, acc[r]);
        }
    }
#pragma unroll
    for (int r = 0; r < 8; ++r) {
        acc[r] += __shfl_xor(acc[r], 32);
        acc[r] += __shfl_xor(acc[r], 16);
        acc[r] += __shfl_xor(acc[r], 8);
        acc[r] += __shfl_xor(acc[r], 4);
        acc[r] += __shfl_xor(acc[r], 2);
        acc[r] += __shfl_xor(acc[r], 1);
    }
    float v = 0.f;
#pragma unroll
    for (int r = 0; r < 8; ++r)
        if (lane == r) v = acc[r];
    if (lane < 8) h1T[(size_t)o * 128 + b0 + lane] = fmaxf(v + b1[o], 0.f);
}

// ---------------------------------------------------------------------------
// Stage 4c: head layer 2: 128 -> 64 per joint, relu. block per output o2,
// 128 threads = batches; weight row via uniform (scalar) loads.
// ---------------------------------------------------------------------------
__global__ __launch_bounds__(128) void head2_k(const float* __restrict__ h1T,
                                               const float* __restrict__ w2,
                                               const float* __restrict__ b2,
                                               float* __restrict__ h2T) {
    const int o2 = blockIdx.x;            // j*64 + h
    const int j = o2 >> 6;
    const int b = threadIdx.x;
    const float* wrow = w2 + (size_t)o2 * 128;
    const float* xcol = h1T + (size_t)j * 128 * 128 + b;
    float acc = b2[o2];
#pragma unroll 16
    for (int k = 0; k < 128; ++k) acc = fmaf(xcol[k * 128], wrow[k], acc);
    h2T[(size_t)o2 * 128 + b] = fmaxf(acc, 0.f);
}

// ---------------------------------------------------------------------------
// Stage 4d: head layer 3 + transpose + pad -> out (B,16,10)
// block per (jj 0..9, oo 0..15), 128 threads = batches.
// ---------------------------------------------------------------------------
__global__ __launch_bounds__(128) void head3_k(const float* __restrict__ h2T,
                                               const float* __restrict__ w3,
                                               const float* __restrict__ b3,
                                               float* __restrict__ out) {
    const int jj = blockIdx.x % 10;
    const int oo = blockIdx.x / 10;
    const int b = threadIdx.x;
    float acc = 0.f;
    if (jj < 6) {
        const float* wrow = w3 + (size_t)(jj * 16 + oo) * 64;
        const float* xcol = h2T + (size_t)jj * 64 * 128 + b;
        acc = b3[jj * 16 + oo];
#pragma unroll 16
        for (int k = 0; k < 64; ++k) acc = fmaf(xcol[k * 128], wrow[k], acc);
    }
    out[(size_t)b * 160 + oo * 10 + jj] = acc;
}

// ---------------------------------------------------------------------------
extern "C" void kernel_launch(void* const* d_in, const int* in_sizes, int n_in,
                              void* d_out, int out_size, void* d_ws, size_t ws_size,
                              hipStream_t stream) {
    const float* images = (const float*)d_in[0];
    const int* tlen = (const int*)d_in[1];
    const float* nfeat = (const float*)d_in[2];
    const int* eidx = (const int*)d_in[3];
    const float* conv_w = (const float*)d_in[4];
    const float* conv_b = (const float*)d_in[5];
    const float* fc1w = (const float*)d_in[6];
    const float* fc1b = (const float*)d_in[7];
    const float* fc2w = (const float*)d_in[8];
    const float* fc2b = (const float*)d_in[9];
    const float* temb = (const float*)d_in[10];
    const float* tfw = (const float*)d_in[11];
    const float* tfb = (const float*)d_in[12];
    const float* e1w = (const float*)d_in[13];
    const float* e1b = (const float*)d_in[14];
    const float* e2w = (const float*)d_in[15];
    const float* e2b = (const float*)d_in[16];
    const float* gcw = (const float*)d_in[17];
    const float* gcb = (const float*)d_in[18];
    const float* lns = (const float*)d_in[19];
    const float* lnb = (const float*)d_in[20];
    const float* pjw = (const float*)d_in[21];
    const float* pjb = (const float*)d_in[22];
    const float* a1w = (const float*)d_in[23];
    const float* a1b = (const float*)d_in[24];
    const float* a2w = (const float*)d_in[25];
    const float* a2b = (const float*)d_in[26];
    const float* w1 = (const float*)d_in[27];
    const float* b1 = (const float*)d_in[28];
    const float* w2 = (const float*)d_in[29];
    const float* b2 = (const float*)d_in[30];
    const float* w3 = (const float*)d_in[31];
    const float* b3 = (const float*)d_in[32];

    const int B = in_sizes[0] / (3 * 224 * 224);  // 128

    float* ws = (float*)d_ws;
    unsigned short* wB = (unsigned short*)d_ws;     // 3072 floats worth
    float* pooled = ws + 3072;                      // B*1568 (dead after fc1)
    float* h1fc = pooled + (size_t)B * 1568;        // B*512
    float* vlm = h1fc + (size_t)B * 512;            // B*768
    float* fused = vlm + (size_t)B * 768;           // B*768
    float* gts = fused + (size_t)B * 768;           // B*320
    float* h1T = pooled;                            // 768*128 (aliases pooled)
    float* h2T = pooled + 98304;                    // 384*128 (aliases pooled)

    wprep<<<1, 256, 0, stream>>>(conv_w, wB);
    conv_mfma<<<dim3(7, B), 512, 0, stream>>>(images, (const unsigned int*)wB,
                                              conv_b, pooled);
    fc1_k<<<(512 * 16) / 4, 256, 0, stream>>>(pooled, fc1w, fc1b, h1fc);
    vlm_k<<<(768 * 16) / 4, 256, 0, stream>>>(h1fc, fc2w, fc2b, tlen, temb, tfw, tfb, vlm);
    graph_k<<<B, 768, 0, stream>>>(nfeat, eidx, e1w, e1b, e2w, e2b, gcw, gcb,
                                   lns, lnb, pjw, pjb, a1w, a1b, a2w, a2b,
                                   vlm, fused, gts);
    head1_k<<<192 * (B / 8), 256, 0, stream>>>(fused, gts, w1, b1, h1T);
    head2_k<<<384, 128, 0, stream>>>(h1T, w2, b2, h2T);
    head3_k<<<160, 128, 0, stream>>>(h2T, w3, b3, (float*)d_out);
}